// Round 4
// baseline (356.263 us; speedup 1.0000x reference)
//
#include <hip/hip_runtime.h>
#include <hip/hip_bf16.h>
#include <stdint.h>

#define NN 8192
#define FIN 512
#define FOUT 256
#define ALPHAV 0.2f
#define MASKF 9e-15f
#define L2E 1.44269504088896340736f

typedef __attribute__((ext_vector_type(8))) short bf16x8;
typedef __attribute__((ext_vector_type(4))) float f32x4;
typedef unsigned long long u64;

static __device__ __forceinline__ float ex2(float x){
#if __has_builtin(__builtin_amdgcn_exp2f)
  return __builtin_amdgcn_exp2f(x);
#else
  return exp2f(x);
#endif
}
static __device__ __forceinline__ unsigned short f2bf(float f){
  __bf16 b = (__bf16)f;
  return __builtin_bit_cast(unsigned short, b);
}

// ---------------- K1: hT(bf16) = (x@W)^T, fused f1 = h@a1, f2 = h@a2 ------
// 512 blocks x 256 thr (2 blocks/CU). x read as wave-broadcast float4.
// W tile staged via regs (T14 async-split: next tile's loads issued right
// after the barrier, consumed next iter). h fp32 never materialized.
__global__ __launch_bounds__(256, 2) void k_gemm_h(
    const float* __restrict__ x, const float* __restrict__ Wm,
    const float* __restrict__ aG, unsigned short* __restrict__ hT,
    float* __restrict__ f1, float* __restrict__ f2)
{
  __shared__ __align__(16) float Bs[4096];   // 16x256 W tile, staging order
  const int t  = threadIdx.x;
  const int rg = t >> 6;          // wave -> 4 rows
  const int cg = t & 63;          // lane -> 4 cols
  const int i0 = blockIdx.x * 16;
  const int wk = t >> 4;          // staging k-row 0..15
  const int wc = (t & 15) * 4;    // staging col within 64-col section

  float acc[4][4];
#pragma unroll
  for (int r = 0; r < 4; ++r)
#pragma unroll
    for (int c = 0; c < 4; ++c) acc[r][c] = 0.f;

  const float* xrow[4];
#pragma unroll
  for (int r = 0; r < 4; ++r) xrow[r] = x + (size_t)(i0 + rg * 4 + r) * FIN;

  float4 wreg[4];
#pragma unroll
  for (int q = 0; q < 4; ++q)
    wreg[q] = *(const float4*)(Wm + (size_t)wk * FOUT + q * 64 + wc);

  for (int k0 = 0; k0 < FIN; k0 += 16) {
    __syncthreads();               // previous readers done
#pragma unroll
    for (int q = 0; q < 4; ++q)
      *(float4*)(&Bs[q * 1024 + t * 4]) = wreg[q];
    __syncthreads();               // Bs ready
    if (k0 + 16 < FIN) {           // prefetch next W tile into regs
#pragma unroll
      for (int q = 0; q < 4; ++q)
        wreg[q] = *(const float4*)(Wm + (size_t)(k0 + 16 + wk) * FOUT + q * 64 + wc);
    }
#pragma unroll
    for (int q = 0; q < 4; ++q) {
      float4 xa[4];
#pragma unroll
      for (int r = 0; r < 4; ++r) xa[r] = *(const float4*)(xrow[r] + k0 + q * 4);
#pragma unroll
      for (int k2 = 0; k2 < 4; ++k2) {
        const int kk = q * 4 + k2;
        float4 bv = *(const float4*)(&Bs[(cg >> 4) * 1024 + kk * 64 + (cg & 15) * 4]);
        float bb4[4] = {bv.x, bv.y, bv.z, bv.w};
#pragma unroll
        for (int r = 0; r < 4; ++r) {
          float ar = (k2 == 0) ? xa[r].x : (k2 == 1) ? xa[r].y : (k2 == 2) ? xa[r].z : xa[r].w;
#pragma unroll
          for (int c = 0; c < 4; ++c) acc[r][c] = fmaf(ar, bb4[c], acc[r][c]);
        }
      }
    }
  }
  // hT (transposed, bf16): 4 rows packed per 8B store
#pragma unroll
  for (int c = 0; c < 4; ++c) {
    int col = cg * 4 + c;
    ushort4 u;
    u.x = f2bf(acc[0][c]); u.y = f2bf(acc[1][c]);
    u.z = f2bf(acc[2][c]); u.w = f2bf(acc[3][c]);
    *(ushort4*)(hT + (size_t)col * NN + i0 + rg * 4) = u;
  }
  // fused f1/f2: per-row dot over this lane's 4 cols, wave shfl reduce
  float4 a1 = *(const float4*)(aG + cg * 4);
  float4 a2 = *(const float4*)(aG + FOUT + cg * 4);
#pragma unroll
  for (int r = 0; r < 4; ++r) {
    float s1 = acc[r][0]*a1.x + acc[r][1]*a1.y + acc[r][2]*a1.z + acc[r][3]*a1.w;
    float s2 = acc[r][0]*a2.x + acc[r][1]*a2.y + acc[r][2]*a2.z + acc[r][3]*a2.w;
#pragma unroll
    for (int off = 32; off > 0; off >>= 1) {
      s1 += __shfl_xor(s1, off);
      s2 += __shfl_xor(s2, off);
    }
    if (cg == 0) { f1[i0 + rg * 4 + r] = s1; f2[i0 + rg * 4 + r] = s2; }
  }
}

// ---------------- K3: per-row max + exp-sum + adj->bitmask ----------------
__global__ __launch_bounds__(256) void k_rowstat(
    const int* __restrict__ adj, const float* __restrict__ f1,
    const float* __restrict__ f2, u64* __restrict__ maskg,
    float* __restrict__ row_m, float* __restrict__ row_inv)
{
  __shared__ float red[8];
  const int i = blockIdx.x;
  const int t = threadIdx.x;
  const int wv = t >> 6;
  const int l = t & 63;
  const float f1i = f1[i];
  const int* arow = adj + (size_t)i * NN + wv * 2048;
  const float* f2w = f2 + wv * 2048;
  unsigned int bits = 0;
  float mloc = -3.0e38f;
  float f2loc[32];
#pragma unroll
  for (int it = 0; it < 32; ++it) {
    int av = arow[it * 64 + l];
    bool bit = av > 0;
    u64 bal = __ballot(bit);
    if (l == 0) maskg[(size_t)i * 128 + wv * 32 + it] = bal;
    float f2j = f2w[it * 64 + l];
    f2loc[it] = f2j;
    float s = f1i + f2j;
    float ls = fmaxf(s, ALPHAV * s);
    float e = bit ? ls : MASKF;
    mloc = fmaxf(mloc, e);
    bits |= (bit ? 1u : 0u) << it;
  }
#pragma unroll
  for (int off = 32; off > 0; off >>= 1) mloc = fmaxf(mloc, __shfl_xor(mloc, off));
  if (l == 0) red[wv] = mloc;
  __syncthreads();
  const float m = fmaxf(fmaxf(red[0], red[1]), fmaxf(red[2], red[3]));
  const float nm = -m * L2E;
  const float cm = ex2(fmaf(MASKF, L2E, nm));
  float sl = 0.f;
#pragma unroll
  for (int it = 0; it < 32; ++it) {
    float s = f1i + f2loc[it];
    float ls = fmaxf(s, ALPHAV * s);
    float pe = ex2(fmaf(ls, L2E, nm));
    sl += ((bits >> it) & 1u) ? pe : cm;
  }
#pragma unroll
  for (int off = 32; off > 0; off >>= 1) sl += __shfl_xor(sl, off);
  __syncthreads();
  if (l == 0) red[4 + wv] = sl;
  __syncthreads();
  if (t == 0) {
    float tot = red[4] + red[5] + red[6] + red[7];
    row_m[i] = m;
    row_inv[i] = 1.f / tot;
  }
}

// ---------------- K4: fused P-regen + (P @ h) via bf16 MFMA ---------------
// No LDS staging, no barriers: B-fragments read DIRECT from global hT
// (L2/L3-resident, 16 full 64B lines per wave-load). grid (64, 8):
// BM=128 (4 waves x 32 rows), BN=256 (no col split -> P-regen once),
// Kslice=1024. 512 blocks = 2 blocks/CU = 2 waves/SIMD, VGPR budget 256.
__global__ __launch_bounds__(256, 2) void k_spmm(
    const unsigned short* __restrict__ hTg,
    const u64* __restrict__ maskg,
    const float* __restrict__ f1, const float* __restrict__ f2,
    const float* __restrict__ row_m,
    float* __restrict__ outp, float* __restrict__ part)
{
  __shared__ __align__(16) float f2s[1024];   // f2 slice, pre-scaled by L2E
  const int t  = threadIdx.x;
  const int wv = t >> 6;
  const int l  = t & 63;
  const int lg = l >> 4;
  const int lm = l & 15;
  const int bx = blockIdx.x;
  const int ks = blockIdx.y;
  const int r0w = bx * 128 + wv * 32;

  {
    float4 v = *(const float4*)(f2 + ks * 1024 + t * 4);
    v.x *= L2E; v.y *= L2E; v.z *= L2E; v.w *= L2E;
    *(float4*)(&f2s[t * 4]) = v;
  }

  const int rA = r0w + lm, rB = r0w + 16 + lm;
  const float nmA = -row_m[rA] * L2E, nmB = -row_m[rB] * L2E;
  const float base0 = fmaf(f1[rA], L2E, nmA), base1 = fmaf(f1[rB], L2E, nmB);
  const float c20 = nmA * (1.f - ALPHAV),     c21 = nmB * (1.f - ALPHAV);
  const float mc0 = fmaf(MASKF, L2E, nmA),    mc1 = fmaf(MASKF, L2E, nmB);
  const u64* mrowA = maskg + (size_t)rA * 128 + ks * 16;
  const u64* mrowB = maskg + (size_t)rB * 128 + ks * 16;

  f32x4 accA[16], accB[16];
#pragma unroll
  for (int nf = 0; nf < 16; ++nf)
#pragma unroll
    for (int e = 0; e < 4; ++e) { accA[nf][e] = 0.f; accB[nf][e] = 0.f; }

  // per-lane base for B-fragment reads: hT[nf*16+lm][ks*1024 + kk + lg*8]
  const unsigned short* hbase = hTg + (size_t)lm * NN + ks * 1024 + lg * 8;

  u64 mA = mrowA[0], mB = mrowB[0];
  __syncthreads();   // f2s ready (only barrier in the kernel)

  for (int jt = 0; jt < 16; ++jt) {
    u64 mAn = 0, mBn = 0;
    if (jt < 15) { mAn = mrowA[jt + 1]; mBn = mrowB[jt + 1]; }
#pragma unroll
    for (int k32 = 0; k32 < 2; ++k32) {
      const int kk = jt * 64 + k32 * 32;    // within 1024-k slice
      // issue all 16 B-fragment loads first (independent, L2 hits)
      bf16x8 bbv[16];
#pragma unroll
      for (int nf = 0; nf < 16; ++nf)
        bbv[nf] = *(const bf16x8*)(hbase + (size_t)nf * 16 * NN + kk);
      // P-regen (covers load latency)
      const int kb = k32 * 32 + lg * 8;
      float4 fA = *(const float4*)(&f2s[kk + lg * 8]);
      float4 fB = *(const float4*)(&f2s[kk + lg * 8 + 4]);
      float fv[8] = {fA.x, fA.y, fA.z, fA.w, fB.x, fB.y, fB.z, fB.w};
      unsigned byA = (unsigned)(mA >> kb) & 0xffu;
      unsigned byB = (unsigned)(mB >> kb) & 0xffu;
      bf16x8 afr0, afr1;
#pragma unroll
      for (int b = 0; b < 8; ++b) {
        float u0 = base0 + fv[b];
        float w0 = fmaxf(u0, fmaf(ALPHAV, u0, c20));
        w0 = (byA & (1u << b)) ? w0 : mc0;
        afr0[b] = (short)f2bf(ex2(w0));
        float u1 = base1 + fv[b];
        float w1 = fmaxf(u1, fmaf(ALPHAV, u1, c21));
        w1 = (byB & (1u << b)) ? w1 : mc1;
        afr1[b] = (short)f2bf(ex2(w1));
      }
#pragma unroll
      for (int nf = 0; nf < 16; ++nf) {
        accA[nf] = __builtin_amdgcn_mfma_f32_16x16x32_bf16(afr0, bbv[nf], accA[nf], 0, 0, 0);
        accB[nf] = __builtin_amdgcn_mfma_f32_16x16x32_bf16(afr1, bbv[nf], accB[nf], 0, 0, 0);
      }
    }
    mA = mAn; mB = mBn;
  }

  float* dst = (ks == 0) ? outp : (part + (size_t)(ks - 1) * NN * FOUT);
#pragma unroll
  for (int nf = 0; nf < 16; ++nf) {
    int col = nf * 16 + lm;
#pragma unroll
    for (int e = 0; e < 4; ++e) {
      int rowA = r0w + lg * 4 + e;
      int rowB = r0w + 16 + lg * 4 + e;
      dst[(size_t)rowA * FOUT + col] = accA[nf][e];
      dst[(size_t)rowB * FOUT + col] = accB[nf][e];
    }
  }
}

// ---------------- K5: sum 7 K-partials, scale by 1/rowsum -----------------
__global__ __launch_bounds__(256) void k_fin(
    float* __restrict__ outp, const float* __restrict__ part,
    const float* __restrict__ row_inv)
{
  const int idx4 = blockIdx.x * 256 + threadIdx.x;
  const size_t e = (size_t)idx4 * 4;
  const int i = (int)(e >> 8);
  float4 o = *(float4*)(outp + e);
#pragma unroll
  for (int p = 0; p < 7; ++p) {
    float4 pv = *(const float4*)(part + (size_t)p * NN * FOUT + e);
    o.x += pv.x; o.y += pv.y; o.z += pv.z; o.w += pv.w;
  }
  float inv = row_inv[i];
  o.x *= inv; o.y *= inv; o.z *= inv; o.w *= inv;
  *(float4*)(outp + e) = o;
}

extern "C" void kernel_launch(void* const* d_in, const int* in_sizes, int n_in,
                              void* d_out, int out_size, void* d_ws, size_t ws_size,
                              hipStream_t stream)
{
  const float* x  = (const float*)d_in[0];
  const int* adj  = (const int*)d_in[1];
  const float* Wm = (const float*)d_in[2];
  const float* aG = (const float*)d_in[3];
  float* outp = (float*)d_out;

  char* w = (char*)d_ws;
  unsigned short* hT = (unsigned short*)(w + 0);             // 4 MB
  float* f1          = (float*)(w + 4194304);                // 32 KB
  float* f2          = (float*)(w + 4227072);                // 32 KB
  float* row_m       = (float*)(w + 4259840);                // 32 KB
  float* row_inv     = (float*)(w + 4292608);                // 32 KB
  u64*   maskg       = (u64*)(w + 4325376);                  // 8 MB
  float* part        = (float*)(w + 12713984);               // 56 MB (7 partials)

  hipLaunchKernelGGL(k_gemm_h,  dim3(512),    dim3(256), 0, stream, x, Wm, aG, hT, f1, f2);
  hipLaunchKernelGGL(k_rowstat, dim3(8192),   dim3(256), 0, stream, adj, f1, f2, maskg, row_m, row_inv);
  hipLaunchKernelGGL(k_spmm,    dim3(64, 8),  dim3(256), 0, stream, hT, maskg, f1, f2, row_m, outp, part);
  hipLaunchKernelGGL(k_fin,     dim3(2048),   dim3(256), 0, stream, outp, part, row_inv);
}

// Round 5
// 271.209 us; speedup vs baseline: 1.3136x; 1.3136x over previous
//
#include <hip/hip_runtime.h>
#include <hip/hip_bf16.h>
#include <stdint.h>

#define NN 8192
#define FIN 512
#define FOUT 256
#define ALPHAV 0.2f
#define MASKF 9e-15f
#define L2E 1.44269504088896340736f

typedef __attribute__((ext_vector_type(8))) short bf16x8;
typedef __attribute__((ext_vector_type(4))) float f32x4;
typedef unsigned long long u64;

static __device__ __forceinline__ float ex2(float x){
#if __has_builtin(__builtin_amdgcn_exp2f)
  return __builtin_amdgcn_exp2f(x);
#else
  return exp2f(x);
#endif
}
static __device__ __forceinline__ unsigned short f2bf(float f){
  __bf16 b = (__bf16)f;
  return __builtin_bit_cast(unsigned short, b);
}

// ---------------- K1: hT(bf16) = (x@W)^T, fused f1 = h@a1, f2 = h@a2 ------
__global__ __launch_bounds__(256, 2) void k_gemm_h(
    const float* __restrict__ x, const float* __restrict__ Wm,
    const float* __restrict__ aG, unsigned short* __restrict__ hT,
    float* __restrict__ f1, float* __restrict__ f2)
{
  __shared__ __align__(16) float Bs[4096];   // 16x256 W tile, staging order
  const int t  = threadIdx.x;
  const int rg = t >> 6;          // wave -> 4 rows
  const int cg = t & 63;          // lane -> 4 cols
  const int i0 = blockIdx.x * 16;
  const int wk = t >> 4;          // staging k-row 0..15
  const int wc = (t & 15) * 4;    // staging col within 64-col section

  float acc[4][4];
#pragma unroll
  for (int r = 0; r < 4; ++r)
#pragma unroll
    for (int c = 0; c < 4; ++c) acc[r][c] = 0.f;

  const float* xrow[4];
#pragma unroll
  for (int r = 0; r < 4; ++r) xrow[r] = x + (size_t)(i0 + rg * 4 + r) * FIN;

  float4 wreg[4];
#pragma unroll
  for (int q = 0; q < 4; ++q)
    wreg[q] = *(const float4*)(Wm + (size_t)wk * FOUT + q * 64 + wc);

  for (int k0 = 0; k0 < FIN; k0 += 16) {
    __syncthreads();               // previous readers done
#pragma unroll
    for (int q = 0; q < 4; ++q)
      *(float4*)(&Bs[q * 1024 + t * 4]) = wreg[q];
    __syncthreads();               // Bs ready
    if (k0 + 16 < FIN) {           // prefetch next W tile into regs
#pragma unroll
      for (int q = 0; q < 4; ++q)
        wreg[q] = *(const float4*)(Wm + (size_t)(k0 + 16 + wk) * FOUT + q * 64 + wc);
    }
#pragma unroll
    for (int q = 0; q < 4; ++q) {
      float4 xa[4];
#pragma unroll
      for (int r = 0; r < 4; ++r) xa[r] = *(const float4*)(xrow[r] + k0 + q * 4);
#pragma unroll
      for (int k2 = 0; k2 < 4; ++k2) {
        const int kk = q * 4 + k2;
        float4 bv = *(const float4*)(&Bs[(cg >> 4) * 1024 + kk * 64 + (cg & 15) * 4]);
        float bb4[4] = {bv.x, bv.y, bv.z, bv.w};
#pragma unroll
        for (int r = 0; r < 4; ++r) {
          float ar = (k2 == 0) ? xa[r].x : (k2 == 1) ? xa[r].y : (k2 == 2) ? xa[r].z : xa[r].w;
#pragma unroll
          for (int c = 0; c < 4; ++c) acc[r][c] = fmaf(ar, bb4[c], acc[r][c]);
        }
      }
    }
  }
#pragma unroll
  for (int c = 0; c < 4; ++c) {
    int col = cg * 4 + c;
    ushort4 u;
    u.x = f2bf(acc[0][c]); u.y = f2bf(acc[1][c]);
    u.z = f2bf(acc[2][c]); u.w = f2bf(acc[3][c]);
    *(ushort4*)(hT + (size_t)col * NN + i0 + rg * 4) = u;
  }
  float4 a1 = *(const float4*)(aG + cg * 4);
  float4 a2 = *(const float4*)(aG + FOUT + cg * 4);
#pragma unroll
  for (int r = 0; r < 4; ++r) {
    float s1 = acc[r][0]*a1.x + acc[r][1]*a1.y + acc[r][2]*a1.z + acc[r][3]*a1.w;
    float s2 = acc[r][0]*a2.x + acc[r][1]*a2.y + acc[r][2]*a2.z + acc[r][3]*a2.w;
#pragma unroll
    for (int off = 32; off > 0; off >>= 1) {
      s1 += __shfl_xor(s1, off);
      s2 += __shfl_xor(s2, off);
    }
    if (cg == 0) { f1[i0 + rg * 4 + r] = s1; f2[i0 + rg * 4 + r] = s2; }
  }
}

// ---------------- K3: per-row max + exp-sum + adj->bitmask ----------------
__global__ __launch_bounds__(256) void k_rowstat(
    const int* __restrict__ adj, const float* __restrict__ f1,
    const float* __restrict__ f2, u64* __restrict__ maskg,
    float* __restrict__ row_m, float* __restrict__ row_inv)
{
  __shared__ float red[8];
  const int i = blockIdx.x;
  const int t = threadIdx.x;
  const int wv = t >> 6;
  const int l = t & 63;
  const float f1i = f1[i];
  const int* arow = adj + (size_t)i * NN + wv * 2048;
  const float* f2w = f2 + wv * 2048;
  unsigned int bits = 0;
  float mloc = -3.0e38f;
  float f2loc[32];
#pragma unroll
  for (int it = 0; it < 32; ++it) {
    int av = arow[it * 64 + l];
    bool bit = av > 0;
    u64 bal = __ballot(bit);
    if (l == 0) maskg[(size_t)i * 128 + wv * 32 + it] = bal;
    float f2j = f2w[it * 64 + l];
    f2loc[it] = f2j;
    float s = f1i + f2j;
    float ls = fmaxf(s, ALPHAV * s);
    float e = bit ? ls : MASKF;
    mloc = fmaxf(mloc, e);
    bits |= (bit ? 1u : 0u) << it;
  }
#pragma unroll
  for (int off = 32; off > 0; off >>= 1) mloc = fmaxf(mloc, __shfl_xor(mloc, off));
  if (l == 0) red[wv] = mloc;
  __syncthreads();
  const float m = fmaxf(fmaxf(red[0], red[1]), fmaxf(red[2], red[3]));
  const float nm = -m * L2E;
  const float cm = ex2(fmaf(MASKF, L2E, nm));
  float sl = 0.f;
#pragma unroll
  for (int it = 0; it < 32; ++it) {
    float s = f1i + f2loc[it];
    float ls = fmaxf(s, ALPHAV * s);
    float pe = ex2(fmaf(ls, L2E, nm));
    sl += ((bits >> it) & 1u) ? pe : cm;
  }
#pragma unroll
  for (int off = 32; off > 0; off >>= 1) sl += __shfl_xor(sl, off);
  __syncthreads();
  if (l == 0) red[4 + wv] = sl;
  __syncthreads();
  if (t == 0) {
    float tot = red[4] + red[5] + red[6] + red[7];
    row_m[i] = m;
    row_inv[i] = 1.f / tot;
  }
}

// ---------------- K4: fused P-regen + (P @ h) via bf16 MFMA ---------------
// T3/T4-lite: triple-buffered LDS (3x16KB), depth-2 prefetch via
// global_load_lds(16B, pre-swizzled source), counted vmcnt(4) (never 0
// in-loop), ONE raw s_barrier per 32-j tile. Masks and f2 preloaded to LDS
// so the loop body's ONLY vmem ops are the 4 staging loads (exact count).
// grid (64, 8): BM=128 (4 waves x 32 rows), BN=256, kslice=1024.
__global__ __launch_bounds__(256, 2) void k_spmm(
    const unsigned short* __restrict__ hTg,
    const u64* __restrict__ maskg,
    const float* __restrict__ f1, const float* __restrict__ f2,
    const float* __restrict__ row_m,
    float* __restrict__ outp, float* __restrict__ part)
{
  __shared__ __align__(16) unsigned short hTs[3 * 8192]; // 3 x (256 x 32) = 48 KB
  __shared__ __align__(16) u64 mskL[16 * 128];           // [word][rowInBlk] 16 KB
  __shared__ __align__(16) float f2s[1024];              // pre-scaled by L2E, 4 KB
  const int t  = threadIdx.x;
  const int wv = t >> 6;
  const int l  = t & 63;
  const int lg = l >> 4;
  const int lm = l & 15;
  const int bx = blockIdx.x;
  const int ks = blockIdx.y;
  const int r0w = bx * 128 + wv * 32;

  // ---- preloads (global->LDS via regs; all consumed before main loop) ----
  {
    float4 v = *(const float4*)(f2 + ks * 1024 + t * 4);
    v.x *= L2E; v.y *= L2E; v.z *= L2E; v.w *= L2E;
    *(float4*)(&f2s[t * 4]) = v;
  }
  {
    const int row = t >> 1;
    const int wbase = (t & 1) * 8;
    const u64* gp = maskg + (size_t)(bx * 128 + row) * 128 + ks * 16 + wbase;
#pragma unroll
    for (int p = 0; p < 8; ++p)
      mskL[(wbase + p) * 128 + row] = gp[p];
  }

  const int rA = r0w + lm, rB = r0w + 16 + lm;
  const float nmA = -row_m[rA] * L2E, nmB = -row_m[rB] * L2E;
  const float base0 = fmaf(f1[rA], L2E, nmA), base1 = fmaf(f1[rB], L2E, nmB);
  const float c20 = nmA * (1.f - ALPHAV),     c21 = nmB * (1.f - ALPHAV);
  const float mc0 = fmaf(MASKF, L2E, nmA),    mc1 = fmaf(MASKF, L2E, nmB);

  f32x4 accA[16], accB[16];
#pragma unroll
  for (int nf = 0; nf < 16; ++nf)
#pragma unroll
    for (int e = 0; e < 4; ++e) { accA[nf][e] = 0.f; accB[nf][e] = 0.f; }

  // staging geometry: chunk c, thread t -> LDS linear bytes c*4096 + t*16
  //   n = c*64 + (t>>2), kbyte_lin = (t&3)*16
  //   source k elems = ((t&3) ^ ((t>>2)&3)) << 3   (XOR swizzle, 16B granule)
  const int srow = t >> 2;
  const int selem = (((t & 3) ^ ((t >> 2) & 3)) << 3);
  const size_t gbase = (size_t)srow * NN + ks * 1024 + selem;

#define STAGE(BUFI, TILE)                                                     \
  do {                                                                        \
    char* lbase_ = ((char*)hTs) + (BUFI) * 16384 + wv * 1024;                 \
    _Pragma("unroll")                                                         \
    for (int c = 0; c < 4; ++c) {                                             \
      const unsigned short* gp = hTg + gbase + (size_t)c * 64 * NN + (TILE) * 32; \
      __builtin_amdgcn_global_load_lds(                                       \
          (const __attribute__((address_space(1))) unsigned int*)gp,          \
          (__attribute__((address_space(3))) unsigned int*)(lbase_ + c * 4096), \
          16, 0, 0);                                                          \
    }                                                                         \
  } while (0)

#define COMP(BUFI, JT)                                                        \
  do {                                                                        \
    const u64 mA_ = mskL[((JT) >> 1) * 128 + wv * 32 + lm];                   \
    const u64 mB_ = mskL[((JT) >> 1) * 128 + wv * 32 + 16 + lm];              \
    const int sh_ = ((JT) & 1) * 32 + lg * 8;                                 \
    const unsigned byA = (unsigned)(mA_ >> sh_) & 0xffu;                      \
    const unsigned byB = (unsigned)(mB_ >> sh_) & 0xffu;                      \
    float4 fA = *(const float4*)(&f2s[(JT) * 32 + lg * 8]);                   \
    float4 fB = *(const float4*)(&f2s[(JT) * 32 + lg * 8 + 4]);               \
    float fv[8] = {fA.x, fA.y, fA.z, fA.w, fB.x, fB.y, fB.z, fB.w};           \
    bf16x8 afr0, afr1;                                                        \
    _Pragma("unroll")                                                         \
    for (int b = 0; b < 8; ++b) {                                             \
      float u0 = base0 + fv[b];                                               \
      float w0 = fmaxf(u0, fmaf(ALPHAV, u0, c20));                            \
      w0 = (byA & (1u << b)) ? w0 : mc0;                                      \
      afr0[b] = (short)f2bf(ex2(w0));                                         \
      float u1 = base1 + fv[b];                                               \
      float w1 = fmaxf(u1, fmaf(ALPHAV, u1, c21));                            \
      w1 = (byB & (1u << b)) ? w1 : mc1;                                      \
      afr1[b] = (short)f2bf(ex2(w1));                                         \
    }                                                                         \
    const char* lb_ = ((const char*)hTs) + (BUFI) * 16384;                    \
    const int kb_ = ((lg ^ (lm & 3)) << 4);                                   \
    __builtin_amdgcn_s_setprio(1);                                            \
    _Pragma("unroll")                                                         \
    for (int nf = 0; nf < 16; ++nf) {                                         \
      bf16x8 bb = *(const bf16x8*)(lb_ + (nf * 16 + lm) * 64 + kb_);          \
      accA[nf] = __builtin_amdgcn_mfma_f32_16x16x32_bf16(afr0, bb, accA[nf], 0, 0, 0); \
      accB[nf] = __builtin_amdgcn_mfma_f32_16x16x32_bf16(afr1, bb, accB[nf], 0, 0, 0); \
    }                                                                         \
    __builtin_amdgcn_s_setprio(0);                                            \
  } while (0)

  STAGE(0, 0);
  STAGE(1, 1);
  asm volatile("s_waitcnt lgkmcnt(0)" ::: "memory");   // preload ds_writes done
  __builtin_amdgcn_s_barrier();

  int ri = 0, si = 2;
#pragma unroll 1
  for (int jt = 0; jt < 31; ++jt) {
    asm volatile("s_waitcnt vmcnt(4)" ::: "memory");   // tile jt staged
    __builtin_amdgcn_sched_barrier(0);
    __builtin_amdgcn_s_barrier();                      // visible to all waves
    __builtin_amdgcn_sched_barrier(0);
    if (jt < 30) STAGE(si, jt + 2);                    // si's readers done at barrier
    COMP(ri, jt);
    ri = (ri == 2) ? 0 : ri + 1;
    si = (si == 2) ? 0 : si + 1;
  }
  asm volatile("s_waitcnt vmcnt(0)" ::: "memory");
  __builtin_amdgcn_sched_barrier(0);
  __builtin_amdgcn_s_barrier();
  COMP(ri, 31);
#undef STAGE
#undef COMP

  float* dst = (ks == 0) ? outp : (part + (size_t)(ks - 1) * NN * FOUT);
#pragma unroll
  for (int nf = 0; nf < 16; ++nf) {
    int col = nf * 16 + lm;
#pragma unroll
    for (int e = 0; e < 4; ++e) {
      int rowA = r0w + lg * 4 + e;
      int rowB = r0w + 16 + lg * 4 + e;
      dst[(size_t)rowA * FOUT + col] = accA[nf][e];
      dst[(size_t)rowB * FOUT + col] = accB[nf][e];
    }
  }
}

// ---------------- K5: sum 7 K-partials, scale by 1/rowsum -----------------
__global__ __launch_bounds__(256) void k_fin(
    float* __restrict__ outp, const float* __restrict__ part,
    const float* __restrict__ row_inv)
{
  const int idx4 = blockIdx.x * 256 + threadIdx.x;
  const size_t e = (size_t)idx4 * 4;
  const int i = (int)(e >> 8);
  float4 o = *(float4*)(outp + e);
#pragma unroll
  for (int p = 0; p < 7; ++p) {
    float4 pv = *(const float4*)(part + (size_t)p * NN * FOUT + e);
    o.x += pv.x; o.y += pv.y; o.z += pv.z; o.w += pv.w;
  }
  float inv = row_inv[i];
  o.x *= inv; o.y *= inv; o.z *= inv; o.w *= inv;
  *(float4*)(outp + e) = o;
}

extern "C" void kernel_launch(void* const* d_in, const int* in_sizes, int n_in,
                              void* d_out, int out_size, void* d_ws, size_t ws_size,
                              hipStream_t stream)
{
  const float* x  = (const float*)d_in[0];
  const int* adj  = (const int*)d_in[1];
  const float* Wm = (const float*)d_in[2];
  const float* aG = (const float*)d_in[3];
  float* outp = (float*)d_out;

  char* w = (char*)d_ws;
  unsigned short* hT = (unsigned short*)(w + 0);             // 4 MB
  float* f1          = (float*)(w + 4194304);                // 32 KB
  float* f2          = (float*)(w + 4227072);                // 32 KB
  float* row_m       = (float*)(w + 4259840);                // 32 KB
  float* row_inv     = (float*)(w + 4292608);                // 32 KB
  u64*   maskg       = (u64*)(w + 4325376);                  // 8 MB
  float* part        = (float*)(w + 12713984);               // 56 MB (7 partials)

  hipLaunchKernelGGL(k_gemm_h,  dim3(512),    dim3(256), 0, stream, x, Wm, aG, hT, f1, f2);
  hipLaunchKernelGGL(k_rowstat, dim3(8192),   dim3(256), 0, stream, adj, f1, f2, maskg, row_m, row_inv);
  hipLaunchKernelGGL(k_spmm,    dim3(64, 8),  dim3(256), 0, stream, hT, maskg, f1, f2, row_m, outp, part);
  hipLaunchKernelGGL(k_fin,     dim3(2048),   dim3(256), 0, stream, outp, part, row_inv);
}

// Round 6
// 270.434 us; speedup vs baseline: 1.3174x; 1.0029x over previous
//
#include <hip/hip_runtime.h>
#include <hip/hip_bf16.h>
#include <stdint.h>

#define NN 8192
#define FIN 512
#define FOUT 256
#define ALPHAV 0.2f
#define MASKF 9e-15f
#define L2E 1.44269504088896340736f

typedef __attribute__((ext_vector_type(8))) short bf16x8;
typedef __attribute__((ext_vector_type(4))) float f32x4;
typedef unsigned long long u64;

static __device__ __forceinline__ float ex2(float x){
#if __has_builtin(__builtin_amdgcn_exp2f)
  return __builtin_amdgcn_exp2f(x);
#else
  return exp2f(x);
#endif
}
static __device__ __forceinline__ unsigned short f2bf(float f){
  __bf16 b = (__bf16)f;
  return __builtin_bit_cast(unsigned short, b);
}

// ---------------- K1: hTt(bf16, tiled) = (x@W)^T, fused f1/f2 -------------
// hTt layout: [ktile=j/32][n=0..255][j&31] — each (256n x 32j) tile is a
// contiguous 16 KB block so spmm staging is a sequential stream.
__global__ __launch_bounds__(256, 2) void k_gemm_h(
    const float* __restrict__ x, const float* __restrict__ Wm,
    const float* __restrict__ aG, unsigned short* __restrict__ hTt,
    float* __restrict__ f1, float* __restrict__ f2)
{
  __shared__ __align__(16) float Bs[4096];   // 16x256 W tile, staging order
  const int t  = threadIdx.x;
  const int rg = t >> 6;          // wave -> 4 rows (j)
  const int cg = t & 63;          // lane -> 4 cols (n)
  const int i0 = blockIdx.x * 16;
  const int wk = t >> 4;          // staging k-row 0..15
  const int wc = (t & 15) * 4;    // staging col within 64-col section

  float acc[4][4];
#pragma unroll
  for (int r = 0; r < 4; ++r)
#pragma unroll
    for (int c = 0; c < 4; ++c) acc[r][c] = 0.f;

  const float* xrow[4];
#pragma unroll
  for (int r = 0; r < 4; ++r) xrow[r] = x + (size_t)(i0 + rg * 4 + r) * FIN;

  float4 wreg[4];
#pragma unroll
  for (int q = 0; q < 4; ++q)
    wreg[q] = *(const float4*)(Wm + (size_t)wk * FOUT + q * 64 + wc);

  for (int k0 = 0; k0 < FIN; k0 += 16) {
    __syncthreads();
#pragma unroll
    for (int q = 0; q < 4; ++q)
      *(float4*)(&Bs[q * 1024 + t * 4]) = wreg[q];
    __syncthreads();
    if (k0 + 16 < FIN) {
#pragma unroll
      for (int q = 0; q < 4; ++q)
        wreg[q] = *(const float4*)(Wm + (size_t)(k0 + 16 + wk) * FOUT + q * 64 + wc);
    }
#pragma unroll
    for (int q = 0; q < 4; ++q) {
      float4 xa[4];
#pragma unroll
      for (int r = 0; r < 4; ++r) xa[r] = *(const float4*)(xrow[r] + k0 + q * 4);
#pragma unroll
      for (int k2 = 0; k2 < 4; ++k2) {
        const int kk = q * 4 + k2;
        float4 bv = *(const float4*)(&Bs[(cg >> 4) * 1024 + kk * 64 + (cg & 15) * 4]);
        float bb4[4] = {bv.x, bv.y, bv.z, bv.w};
#pragma unroll
        for (int r = 0; r < 4; ++r) {
          float ar = (k2 == 0) ? xa[r].x : (k2 == 1) ? xa[r].y : (k2 == 2) ? xa[r].z : xa[r].w;
#pragma unroll
          for (int c = 0; c < 4; ++c) acc[r][c] = fmaf(ar, bb4[c], acc[r][c]);
        }
      }
    }
  }
  // tiled store: element (n=col, j) -> hTt[(j>>5)*8192 + col*32 + (j&31)]
  const int j0 = i0 + rg * 4;
  const int kt = j0 >> 5;
  const int jin = j0 & 31;
#pragma unroll
  for (int c = 0; c < 4; ++c) {
    int col = cg * 4 + c;
    ushort4 u;
    u.x = f2bf(acc[0][c]); u.y = f2bf(acc[1][c]);
    u.z = f2bf(acc[2][c]); u.w = f2bf(acc[3][c]);
    *(ushort4*)(hTt + (size_t)kt * 8192 + col * 32 + jin) = u;
  }
  float4 a1 = *(const float4*)(aG + cg * 4);
  float4 a2 = *(const float4*)(aG + FOUT + cg * 4);
#pragma unroll
  for (int r = 0; r < 4; ++r) {
    float s1 = acc[r][0]*a1.x + acc[r][1]*a1.y + acc[r][2]*a1.z + acc[r][3]*a1.w;
    float s2 = acc[r][0]*a2.x + acc[r][1]*a2.y + acc[r][2]*a2.z + acc[r][3]*a2.w;
#pragma unroll
    for (int off = 32; off > 0; off >>= 1) {
      s1 += __shfl_xor(s1, off);
      s2 += __shfl_xor(s2, off);
    }
    if (cg == 0) { f1[i0 + rg * 4 + r] = s1; f2[i0 + rg * 4 + r] = s2; }
  }
}

// ---------------- K2: row-max UPPER BOUND m̂_i = lrelu(f1_i + max f2) ------
// Softmax is shift-invariant: any m >= true masked row-max is exact.
__global__ __launch_bounds__(1024) void k_bound(
    const float* __restrict__ f1, const float* __restrict__ f2,
    float* __restrict__ mhat)
{
  __shared__ float red[16];
  const int t = threadIdx.x;
  float m = -3.0e38f;
#pragma unroll
  for (int k = 0; k < 8; ++k) m = fmaxf(m, f2[t + k * 1024]);
#pragma unroll
  for (int off = 32; off > 0; off >>= 1) m = fmaxf(m, __shfl_xor(m, off));
  if ((t & 63) == 0) red[t >> 6] = m;
  __syncthreads();
  float fm = red[0];
#pragma unroll
  for (int w = 1; w < 16; ++w) fm = fmaxf(fm, red[w]);
#pragma unroll
  for (int k = 0; k < 8; ++k) {
    int i = t + k * 1024;
    float s = f1[i] + fm;
    mhat[i] = fmaxf(fmaxf(s, ALPHAV * s), MASKF);
  }
}

// ---------------- K3: FUSED adj-stream + P-regen + (P@h) MFMA + rowsums ---
// grid (64, 8): BM=128 (4 waves x 32 rows), BN=256, kslice=1024.
// adj read DIRECT from HBM (once, coalesced), P = exp2((lrelu(f1+f2)-m̂)·lg e)
// regenerated in-register; hTt staged via global_load_lds from the TILED
// layout (sequential 16 KB blocks); counted vmcnt(4), 4 LDS buffers,
// one barrier per tile; row sums of P accumulated alongside.
__global__ __launch_bounds__(256, 2) void k_spmm(
    const unsigned short* __restrict__ hTt,
    const int* __restrict__ adj,
    const float* __restrict__ f1, const float* __restrict__ f2,
    const float* __restrict__ mhat,
    float* __restrict__ part, float* __restrict__ rowsumP)
{
  __shared__ __align__(16) unsigned short hTs[4 * 8192]; // 4 x 16 KB
  __shared__ __align__(16) float f2s[1024];              // pre-scaled by L2E
  const int t  = threadIdx.x;
  const int wv = t >> 6;
  const int l  = t & 63;
  const int lg = l >> 4;
  const int lm = l & 15;
  const int bx = blockIdx.x;
  const int ks = blockIdx.y;
  const int r0w = bx * 128 + wv * 32;

  {
    float4 v = *(const float4*)(f2 + ks * 1024 + t * 4);
    v.x *= L2E; v.y *= L2E; v.z *= L2E; v.w *= L2E;
    *(float4*)(&f2s[t * 4]) = v;
  }

  const int rA = r0w + lm, rB = r0w + 16 + lm;
  const float nmA = -mhat[rA] * L2E,          nmB = -mhat[rB] * L2E;
  const float base0 = fmaf(f1[rA], L2E, nmA), base1 = fmaf(f1[rB], L2E, nmB);
  const float c20 = nmA * (1.f - ALPHAV),     c21 = nmB * (1.f - ALPHAV);
  const float mc0 = fmaf(MASKF, L2E, nmA),    mc1 = fmaf(MASKF, L2E, nmB);
  const int* aPA = adj + (size_t)rA * NN + ks * 1024 + lg * 8;
  const int* aPB = adj + (size_t)rB * NN + ks * 1024 + lg * 8;

  f32x4 accA[16], accB[16];
#pragma unroll
  for (int nf = 0; nf < 16; ++nf)
#pragma unroll
    for (int e = 0; e < 4; ++e) { accA[nf][e] = 0.f; accB[nf][e] = 0.f; }
  float sumA = 0.f, sumB = 0.f;

  // staging: thread t -> LDS byte c*4096 + t*16; n = c*64 + (t>>2),
  // phys granule t&3 holds logical granule (t&3)^(n&3) (XOR swizzle).
  const int sbase = (t >> 2) * 32 + (((t & 3) ^ ((t >> 2) & 3)) << 3);
  const unsigned short* gtile0 = hTt + (size_t)(ks * 32) * 8192 + sbase;

  int4 xa0, xa1, xb0, xb1;   // adj set X (even tiles)
  int4 ya0, ya1, yb0, yb1;   // adj set Y (odd tiles)

#define SB0 __builtin_amdgcn_sched_barrier(0)
#define WAIT4 do { asm volatile("s_waitcnt vmcnt(4)" ::: "memory"); SB0; \
                   __builtin_amdgcn_s_barrier(); SB0; } while (0)
#define WAIT0 do { asm volatile("s_waitcnt vmcnt(0)" ::: "memory"); SB0; \
                   __builtin_amdgcn_s_barrier(); SB0; } while (0)
#define ADJX(J) do { xa0 = *(const int4*)(aPA + (J)*32); \
                     xa1 = *(const int4*)(aPA + (J)*32 + 4); \
                     xb0 = *(const int4*)(aPB + (J)*32); \
                     xb1 = *(const int4*)(aPB + (J)*32 + 4); SB0; } while (0)
#define ADJY(J) do { ya0 = *(const int4*)(aPA + (J)*32); \
                     ya1 = *(const int4*)(aPA + (J)*32 + 4); \
                     yb0 = *(const int4*)(aPB + (J)*32); \
                     yb1 = *(const int4*)(aPB + (J)*32 + 4); SB0; } while (0)
#define STAGE(BUF, J)                                                         \
  do {                                                                        \
    const unsigned short* gp_ = gtile0 + (size_t)(J) * 8192;                  \
    char* lp_ = ((char*)hTs) + (BUF) * 16384 + t * 16;                        \
    _Pragma("unroll")                                                         \
    for (int c = 0; c < 4; ++c) {                                             \
      __builtin_amdgcn_global_load_lds(                                       \
          (const __attribute__((address_space(1))) unsigned int*)(gp_ + c * 2048), \
          (__attribute__((address_space(3))) unsigned int*)(lp_ + c * 4096),  \
          16, 0, 0);                                                          \
    }                                                                         \
    SB0;                                                                      \
  } while (0)

#define COMP(BUF, J, A0, A1, B0, B1)                                          \
  do {                                                                        \
    float4 fA = *(const float4*)(&f2s[(J) * 32 + lg * 8]);                    \
    float4 fB = *(const float4*)(&f2s[(J) * 32 + lg * 8 + 4]);                \
    float fv[8] = {fA.x, fA.y, fA.z, fA.w, fB.x, fB.y, fB.z, fB.w};           \
    int av[8] = {A0.x, A0.y, A0.z, A0.w, A1.x, A1.y, A1.z, A1.w};             \
    int bv[8] = {B0.x, B0.y, B0.z, B0.w, B1.x, B1.y, B1.z, B1.w};             \
    bf16x8 afr0, afr1;                                                        \
    _Pragma("unroll")                                                         \
    for (int b = 0; b < 8; ++b) {                                             \
      float u0 = base0 + fv[b];                                               \
      float w0 = fmaxf(u0, fmaf(ALPHAV, u0, c20));                            \
      w0 = (av[b] > 0) ? w0 : mc0;                                            \
      float p0 = ex2(w0);                                                     \
      sumA += p0;                                                             \
      afr0[b] = (short)f2bf(p0);                                              \
      float u1 = base1 + fv[b];                                               \
      float w1 = fmaxf(u1, fmaf(ALPHAV, u1, c21));                            \
      w1 = (bv[b] > 0) ? w1 : mc1;                                            \
      float p1 = ex2(w1);                                                     \
      sumB += p1;                                                             \
      afr1[b] = (short)f2bf(p1);                                              \
    }                                                                         \
    const char* lb_ = ((const char*)hTs) + (BUF) * 16384;                     \
    const int kb_ = ((lg ^ (lm & 3)) << 4);                                   \
    __builtin_amdgcn_s_setprio(1);                                            \
    _Pragma("unroll")                                                         \
    for (int nf = 0; nf < 16; ++nf) {                                         \
      bf16x8 bb = *(const bf16x8*)(lb_ + (nf * 16 + lm) * 64 + kb_);          \
      accA[nf] = __builtin_amdgcn_mfma_f32_16x16x32_bf16(afr0, bb, accA[nf], 0, 0, 0); \
      accB[nf] = __builtin_amdgcn_mfma_f32_16x16x32_bf16(afr1, bb, accB[nf], 0, 0, 0); \
    }                                                                         \
    __builtin_amdgcn_s_setprio(0);                                            \
  } while (0)

  // prologue: order = [adjX(0) x4, stage(0) x4, stage(1) x4]
  ADJX(0);
  STAGE(0, 0);
  STAGE(1, 1);
  asm volatile("s_waitcnt lgkmcnt(0)" ::: "memory");  // f2s ds_writes done
  SB0;

#pragma unroll 1
  for (int p = 0; p < 7; ++p) {
    const int j0 = p * 4;
    WAIT4; ADJY(j0 + 1); STAGE(2, j0 + 2); COMP(0, j0 + 0, xa0, xa1, xb0, xb1);
    WAIT4; ADJX(j0 + 2); STAGE(3, j0 + 3); COMP(1, j0 + 1, ya0, ya1, yb0, yb1);
    WAIT4; ADJY(j0 + 3); STAGE(0, j0 + 4); COMP(2, j0 + 2, xa0, xa1, xb0, xb1);
    WAIT4; ADJX(j0 + 4); STAGE(1, j0 + 5); COMP(3, j0 + 3, ya0, ya1, yb0, yb1);
  }
  // tail: tiles 28..31
  WAIT4; ADJY(29); STAGE(2, 30); COMP(0, 28, xa0, xa1, xb0, xb1);
  WAIT4; ADJX(30); STAGE(3, 31); COMP(1, 29, ya0, ya1, yb0, yb1);
  WAIT4; ADJY(31);               COMP(2, 30, xa0, xa1, xb0, xb1);
  WAIT0;                         COMP(3, 31, ya0, ya1, yb0, yb1);

#undef SB0
#undef WAIT4
#undef WAIT0
#undef ADJX
#undef ADJY
#undef STAGE
#undef COMP

  // row sums: reduce over lg (lane bits 4-5)
  sumA += __shfl_xor(sumA, 16); sumA += __shfl_xor(sumA, 32);
  sumB += __shfl_xor(sumB, 16); sumB += __shfl_xor(sumB, 32);
  if (lg == 0) {
    rowsumP[(size_t)ks * NN + rA] = sumA;
    rowsumP[(size_t)ks * NN + rB] = sumB;
  }

  float* dst = part + (size_t)ks * NN * FOUT;
#pragma unroll
  for (int nf = 0; nf < 16; ++nf) {
    int col = nf * 16 + lm;
#pragma unroll
    for (int e = 0; e < 4; ++e) {
      int rowA = r0w + lg * 4 + e;
      int rowB = r0w + 16 + lg * 4 + e;
      dst[(size_t)rowA * FOUT + col] = accA[nf][e];
      dst[(size_t)rowB * FOUT + col] = accB[nf][e];
    }
  }
}

// ---------------- K4: sum 8 K-partials + rowsums, normalize ---------------
__global__ __launch_bounds__(256) void k_fin(
    float* __restrict__ outp, const float* __restrict__ part,
    const float* __restrict__ rowsumP)
{
  const int idx4 = blockIdx.x * 256 + threadIdx.x;
  const size_t e = (size_t)idx4 * 4;
  const int i = (int)(e >> 8);
  float rs = 0.f;
#pragma unroll
  for (int p = 0; p < 8; ++p) rs += rowsumP[(size_t)p * NN + i];
  float4 o = {0.f, 0.f, 0.f, 0.f};
#pragma unroll
  for (int p = 0; p < 8; ++p) {
    float4 pv = *(const float4*)(part + (size_t)p * NN * FOUT + e);
    o.x += pv.x; o.y += pv.y; o.z += pv.z; o.w += pv.w;
  }
  float inv = 1.f / rs;
  o.x *= inv; o.y *= inv; o.z *= inv; o.w *= inv;
  *(float4*)(outp + e) = o;
}

extern "C" void kernel_launch(void* const* d_in, const int* in_sizes, int n_in,
                              void* d_out, int out_size, void* d_ws, size_t ws_size,
                              hipStream_t stream)
{
  const float* x  = (const float*)d_in[0];
  const int* adj  = (const int*)d_in[1];
  const float* Wm = (const float*)d_in[2];
  const float* aG = (const float*)d_in[3];
  float* outp = (float*)d_out;

  char* w = (char*)d_ws;
  unsigned short* hTt = (unsigned short*)(w + 0);            // 4 MB (tiled)
  float* f1           = (float*)(w + 4194304);               // 32 KB
  float* f2           = (float*)(w + 4227072);               // 32 KB
  float* mhat         = (float*)(w + 4259840);               // 32 KB
  float* rowsumP      = (float*)(w + 4292608);               // 256 KB
  float* part         = (float*)(w + 4554752);               // 64 MB (8 slices)

  hipLaunchKernelGGL(k_gemm_h, dim3(512),   dim3(256),  0, stream, x, Wm, aG, hTt, f1, f2);
  hipLaunchKernelGGL(k_bound,  dim3(1),     dim3(1024), 0, stream, f1, f2, mhat);
  hipLaunchKernelGGL(k_spmm,   dim3(64, 8), dim3(256),  0, stream, hTt, adj, f1, f2, mhat, part, rowsumP);
  hipLaunchKernelGGL(k_fin,    dim3(2048),  dim3(256),  0, stream, outp, part, rowsumP);
}

// Round 7
// 209.360 us; speedup vs baseline: 1.7017x; 1.2917x over previous
//
#include <hip/hip_runtime.h>
#include <hip/hip_bf16.h>
#include <stdint.h>

#define NN 8192
#define FIN 512
#define FOUT 256
#define ALPHAV 0.2f
#define MASKF 9e-15f
#define L2E 1.44269504088896340736f

typedef __attribute__((ext_vector_type(8))) short bf16x8;
typedef __attribute__((ext_vector_type(4))) float f32x4;
typedef unsigned long long u64;

static __device__ __forceinline__ float ex2(float x){
#if __has_builtin(__builtin_amdgcn_exp2f)
  return __builtin_amdgcn_exp2f(x);
#else
  return exp2f(x);
#endif
}
static __device__ __forceinline__ unsigned short f2bf(float f){
  __bf16 b = (__bf16)f;
  return __builtin_bit_cast(unsigned short, b);
}

// ---------------- K1: hTt(bf16, tiled) = (x@W)^T, fused f1/f2 -------------
// x staged into LDS once (broadcast reads are bank-free); W tile reg-
// prefetched. No global loads inside the k-loop.
__global__ __launch_bounds__(256, 2) void k_gemm_h(
    const float* __restrict__ x, const float* __restrict__ Wm,
    const float* __restrict__ aG, unsigned short* __restrict__ hTt,
    float* __restrict__ f1, float* __restrict__ f2)
{
  __shared__ __align__(16) float Bs[4096];   // 16x256 W tile, staging order
  __shared__ __align__(16) float xs[8192];   // 16 rows x 512 k (32 KB)
  const int t  = threadIdx.x;
  const int rg = t >> 6;          // wave -> 4 rows (j)
  const int cg = t & 63;          // lane -> 4 cols (n)
  const int i0 = blockIdx.x * 16;
  const int wk = t >> 4;
  const int wc = (t & 15) * 4;

  // stage x[i0..i0+16][0..512] -> xs (8 x 16B per thread, sequential)
  {
    const int xr = t >> 7;          // 0..1
    const int xc = (t & 127) * 4;   // 0..508
#pragma unroll
    for (int c = 0; c < 8; ++c) {
      const float* gp = x + (size_t)(i0 + c * 2 + xr) * FIN + xc;
      char* lp = ((char*)xs) + c * 4096 + t * 16;
      __builtin_amdgcn_global_load_lds(
          (const __attribute__((address_space(1))) unsigned int*)gp,
          (__attribute__((address_space(3))) unsigned int*)lp, 16, 0, 0);
    }
  }

  float acc[4][4];
#pragma unroll
  for (int r = 0; r < 4; ++r)
#pragma unroll
    for (int c = 0; c < 4; ++c) acc[r][c] = 0.f;

  float4 wreg[4];
#pragma unroll
  for (int q = 0; q < 4; ++q)
    wreg[q] = *(const float4*)(Wm + (size_t)wk * FOUT + q * 64 + wc);

  for (int k0 = 0; k0 < FIN; k0 += 16) {
    __syncthreads();               // first iter: xs landed (vmcnt0 in sync)
#pragma unroll
    for (int q = 0; q < 4; ++q)
      *(float4*)(&Bs[q * 1024 + t * 4]) = wreg[q];
    __syncthreads();
    if (k0 + 16 < FIN) {
#pragma unroll
      for (int q = 0; q < 4; ++q)
        wreg[q] = *(const float4*)(Wm + (size_t)(k0 + 16 + wk) * FOUT + q * 64 + wc);
    }
#pragma unroll
    for (int q = 0; q < 4; ++q) {
      float4 xa[4];
#pragma unroll
      for (int r = 0; r < 4; ++r)
        xa[r] = *(const float4*)(&xs[(rg * 4 + r) * 512 + k0 + q * 4]);
#pragma unroll
      for (int k2 = 0; k2 < 4; ++k2) {
        const int kk = q * 4 + k2;
        float4 bv = *(const float4*)(&Bs[(cg >> 4) * 1024 + kk * 64 + (cg & 15) * 4]);
        float bb4[4] = {bv.x, bv.y, bv.z, bv.w};
#pragma unroll
        for (int r = 0; r < 4; ++r) {
          float ar = (k2 == 0) ? xa[r].x : (k2 == 1) ? xa[r].y : (k2 == 2) ? xa[r].z : xa[r].w;
#pragma unroll
          for (int c = 0; c < 4; ++c) acc[r][c] = fmaf(ar, bb4[c], acc[r][c]);
        }
      }
    }
  }
  // tiled store: element (n=col, j) -> hTt[(j>>5)*8192 + col*32 + (j&31)]
  const int j0 = i0 + rg * 4;
  const int kt = j0 >> 5;
  const int jin = j0 & 31;
#pragma unroll
  for (int c = 0; c < 4; ++c) {
    int col = cg * 4 + c;
    ushort4 u;
    u.x = f2bf(acc[0][c]); u.y = f2bf(acc[1][c]);
    u.z = f2bf(acc[2][c]); u.w = f2bf(acc[3][c]);
    *(ushort4*)(hTt + (size_t)kt * 8192 + col * 32 + jin) = u;
  }
  float4 a1 = *(const float4*)(aG + cg * 4);
  float4 a2 = *(const float4*)(aG + FOUT + cg * 4);
#pragma unroll
  for (int r = 0; r < 4; ++r) {
    float s1 = acc[r][0]*a1.x + acc[r][1]*a1.y + acc[r][2]*a1.z + acc[r][3]*a1.w;
    float s2 = acc[r][0]*a2.x + acc[r][1]*a2.y + acc[r][2]*a2.z + acc[r][3]*a2.w;
#pragma unroll
    for (int off = 32; off > 0; off >>= 1) {
      s1 += __shfl_xor(s1, off);
      s2 += __shfl_xor(s2, off);
    }
    if (cg == 0) { f1[i0 + rg * 4 + r] = s1; f2[i0 + rg * 4 + r] = s2; }
  }
}

// ---------------- K2: row-max UPPER BOUND m̂_i = lrelu(f1_i + max f2) ------
__global__ __launch_bounds__(1024) void k_bound(
    const float* __restrict__ f1, const float* __restrict__ f2,
    float* __restrict__ mhat)
{
  __shared__ float red[16];
  const int t = threadIdx.x;
  float m = -3.0e38f;
#pragma unroll
  for (int k = 0; k < 8; ++k) m = fmaxf(m, f2[t + k * 1024]);
#pragma unroll
  for (int off = 32; off > 0; off >>= 1) m = fmaxf(m, __shfl_xor(m, off));
  if ((t & 63) == 0) red[t >> 6] = m;
  __syncthreads();
  float fm = red[0];
#pragma unroll
  for (int w = 1; w < 16; ++w) fm = fmaxf(fm, red[w]);
#pragma unroll
  for (int k = 0; k < 8; ++k) {
    int i = t + k * 1024;
    float s = f1[i] + fm;
    mhat[i] = fmaxf(fmaxf(s, ALPHAV * s), MASKF);
  }
}

// ---------------- K3: FUSED adj-stream + P-regen + (P@h) MFMA + rowsums ---
// Slim waves: 1 A-frag/wave (16 rows, acc=64 regs), 4-wave blocks, BM=64,
// grid (128,8) = 1024 blocks = 4 blocks/CU = 16 waves/CU. 2 LDS buffers,
// counted vmcnt(4) (never 0 in-loop), 2 raw barriers/tile. adj per-lane
// direct (each element used by exactly one lane), depth-1 X/Y prefetch.
// Swizzle: phys granule = lg ^ ((n>>1)&3) -> 2-way banks (free).
__global__ __launch_bounds__(256, 4) void k_spmm(
    const unsigned short* __restrict__ hTt,
    const int* __restrict__ adj,
    const float* __restrict__ f1, const float* __restrict__ f2,
    const float* __restrict__ mhat,
    float* __restrict__ part, float* __restrict__ rowsumP)
{
  __shared__ __align__(16) unsigned short hbuf[2][8192]; // 2 x 16 KB
  __shared__ __align__(16) float f2s[1024];              // pre-scaled by L2E
  const int t  = threadIdx.x;
  const int wv = t >> 6;
  const int l  = t & 63;
  const int lg = l >> 4;
  const int lm = l & 15;
  const int bx = blockIdx.x;
  const int ks = blockIdx.y;
  const int r0 = bx * 64 + wv * 16;
  const int rA = r0 + lm;

  {
    float4 v = *(const float4*)(f2 + ks * 1024 + t * 4);
    v.x *= L2E; v.y *= L2E; v.z *= L2E; v.w *= L2E;
    *(float4*)(&f2s[t * 4]) = v;
  }

  const float nmA   = -mhat[rA] * L2E;
  const float base0 = fmaf(f1[rA], L2E, nmA);
  const float c20   = nmA * (1.f - ALPHAV);
  const float mc0   = fmaf(MASKF, L2E, nmA);
  const int* aP = adj + (size_t)rA * NN + ks * 1024 + lg * 8;

  f32x4 acc[16];
#pragma unroll
  for (int nf = 0; nf < 16; ++nf)
#pragma unroll
    for (int e = 0; e < 4; ++e) acc[nf][e] = 0.f;
  float sumP = 0.f;

  // staging: shot c, thread t -> LDS byte c*4096 + t*16; n = c*64 + (t>>2);
  // source granule pre-swizzled: (t&3) ^ ((n>>1)&3), (n>>1)&3 == ((t>>2)>>1)&3
  const int sn  = t >> 2;
  const int ssw = (((t & 3) ^ ((sn >> 1) & 3)) << 3);
  const unsigned short* gt0 = hTt + (size_t)ks * 32 * 8192 + sn * 32 + ssw;

  int4 xA0, xA1, yA0, yA1;

#define SB0 __builtin_amdgcn_sched_barrier(0)
#define SYNC1 do { asm volatile("s_waitcnt lgkmcnt(0)" ::: "memory"); \
                   __builtin_amdgcn_s_barrier(); SB0; } while (0)
#define WAITBAR4 do { asm volatile("s_waitcnt vmcnt(4)" ::: "memory"); \
                      __builtin_amdgcn_s_barrier(); SB0; } while (0)
#define WAITBAR0 do { asm volatile("s_waitcnt vmcnt(0)" ::: "memory"); \
                      __builtin_amdgcn_s_barrier(); SB0; } while (0)
#define ADJX(JT) do { xA0 = *(const int4*)(aP + (JT) * 32); \
                      xA1 = *(const int4*)(aP + (JT) * 32 + 4); } while (0)
#define ADJY(JT) do { yA0 = *(const int4*)(aP + (JT) * 32); \
                      yA1 = *(const int4*)(aP + (JT) * 32 + 4); } while (0)
#define STAGE(BUFI, JT)                                                       \
  do {                                                                        \
    const unsigned short* gp_ = gt0 + (size_t)(JT) * 8192;                    \
    char* lp_ = ((char*)hbuf) + (BUFI) * 16384 + t * 16;                      \
    _Pragma("unroll")                                                         \
    for (int c = 0; c < 4; ++c) {                                             \
      __builtin_amdgcn_global_load_lds(                                       \
          (const __attribute__((address_space(1))) unsigned int*)(gp_ + c * 2048), \
          (__attribute__((address_space(3))) unsigned int*)(lp_ + c * 4096),  \
          16, 0, 0);                                                          \
    }                                                                         \
  } while (0)

#define COMP(BUFI, JT, A0, A1)                                                \
  do {                                                                        \
    float4 fA_ = *(const float4*)(&f2s[(JT) * 32 + lg * 8]);                  \
    float4 fB_ = *(const float4*)(&f2s[(JT) * 32 + lg * 8 + 4]);              \
    float fv_[8] = {fA_.x, fA_.y, fA_.z, fA_.w, fB_.x, fB_.y, fB_.z, fB_.w};  \
    int av_[8] = {A0.x, A0.y, A0.z, A0.w, A1.x, A1.y, A1.z, A1.w};            \
    bf16x8 afr_;                                                              \
    _Pragma("unroll")                                                         \
    for (int b = 0; b < 8; ++b) {                                             \
      float u_ = base0 + fv_[b];                                              \
      float w_ = fmaxf(u_, fmaf(ALPHAV, u_, c20));                            \
      w_ = (av_[b] > 0) ? w_ : mc0;                                           \
      float p_ = ex2(w_);                                                     \
      sumP += p_;                                                             \
      afr_[b] = (short)f2bf(p_);                                              \
    }                                                                         \
    const char* lb_ = (const char*)(&hbuf[BUFI][0]);                          \
    const int kb_ = ((lg ^ ((lm >> 1) & 3)) << 4);                            \
    __builtin_amdgcn_s_setprio(1);                                            \
    _Pragma("unroll")                                                         \
    for (int nf = 0; nf < 16; ++nf) {                                         \
      bf16x8 bb_ = *(const bf16x8*)(lb_ + (nf * 16 + lm) * 64 + kb_);         \
      acc[nf] = __builtin_amdgcn_mfma_f32_16x16x32_bf16(afr_, bb_, acc[nf], 0, 0, 0); \
    }                                                                         \
    __builtin_amdgcn_s_setprio(0);                                            \
  } while (0)

  // drain prologue loads so the counted vmem stream below is exact
  asm volatile("s_waitcnt vmcnt(0)" ::: "memory");
  SB0;
  ADJX(0);
  STAGE(0, 0);

#pragma unroll 1
  for (int p = 0; p < 15; ++p) {
    const int jt = p * 2;
    SYNC1;                    // all waves done reading hbuf[1] (prev COMP)
    STAGE(1, jt + 1);
    WAITBAR4;                 // HT(jt)+ADJ(jt) landed chip-wide; HT(jt+1) flying
    ADJY(jt + 1);
    COMP(0, jt, xA0, xA1);
    SYNC1;
    STAGE(0, jt + 2);
    WAITBAR4;
    ADJX(jt + 2);
    COMP(1, jt + 1, yA0, yA1);
  }
  // tiles 30, 31
  SYNC1;
  STAGE(1, 31);
  WAITBAR4;
  ADJY(31);
  COMP(0, 30, xA0, xA1);
  SYNC1;
  WAITBAR0;
  COMP(1, 31, yA0, yA1);

#undef SB0
#undef SYNC1
#undef WAITBAR4
#undef WAITBAR0
#undef ADJX
#undef ADJY
#undef STAGE
#undef COMP

  // row sums: reduce over lg (lane bits 4-5)
  sumP += __shfl_xor(sumP, 16);
  sumP += __shfl_xor(sumP, 32);
  if (lg == 0) rowsumP[(size_t)ks * NN + rA] = sumP;

  float* dst = part + (size_t)ks * NN * FOUT;
#pragma unroll
  for (int nf = 0; nf < 16; ++nf) {
    int col = nf * 16 + lm;
#pragma unroll
    for (int e = 0; e < 4; ++e) {
      int row = r0 + lg * 4 + e;
      dst[(size_t)row * FOUT + col] = acc[nf][e];
    }
  }
}

// ---------------- K4: sum 8 K-partials + rowsums, normalize ---------------
__global__ __launch_bounds__(256) void k_fin(
    float* __restrict__ outp, const float* __restrict__ part,
    const float* __restrict__ rowsumP)
{
  const int idx4 = blockIdx.x * 256 + threadIdx.x;
  const size_t e = (size_t)idx4 * 4;
  const int i = (int)(e >> 8);
  float rs = 0.f;
#pragma unroll
  for (int p = 0; p < 8; ++p) rs += rowsumP[(size_t)p * NN + i];
  float4 o = {0.f, 0.f, 0.f, 0.f};
#pragma unroll
  for (int p = 0; p < 8; ++p) {
    float4 pv = *(const float4*)(part + (size_t)p * NN * FOUT + e);
    o.x += pv.x; o.y += pv.y; o.z += pv.z; o.w += pv.w;
  }
  float inv = 1.f / rs;
  o.x *= inv; o.y *= inv; o.z *= inv; o.w *= inv;
  *(float4*)(outp + e) = o;
}

extern "C" void kernel_launch(void* const* d_in, const int* in_sizes, int n_in,
                              void* d_out, int out_size, void* d_ws, size_t ws_size,
                              hipStream_t stream)
{
  const float* x  = (const float*)d_in[0];
  const int* adj  = (const int*)d_in[1];
  const float* Wm = (const float*)d_in[2];
  const float* aG = (const float*)d_in[3];
  float* outp = (float*)d_out;

  char* w = (char*)d_ws;
  unsigned short* hTt = (unsigned short*)(w + 0);            // 4 MB (tiled)
  float* f1           = (float*)(w + 4194304);               // 32 KB
  float* f2           = (float*)(w + 4227072);               // 32 KB
  float* mhat         = (float*)(w + 4259840);               // 32 KB
  float* rowsumP      = (float*)(w + 4292608);               // 256 KB
  float* part         = (float*)(w + 4554752);               // 64 MB (8 slices)

  hipLaunchKernelGGL(k_gemm_h, dim3(512),    dim3(256),  0, stream, x, Wm, aG, hTt, f1, f2);
  hipLaunchKernelGGL(k_bound,  dim3(1),      dim3(1024), 0, stream, f1, f2, mhat);
  hipLaunchKernelGGL(k_spmm,   dim3(128, 8), dim3(256),  0, stream, hTt, adj, f1, f2, mhat, part, rowsumP);
  hipLaunchKernelGGL(k_fin,    dim3(2048),   dim3(256),  0, stream, outp, part, rowsumP);
}